// Round 7
// baseline (749.829 us; speedup 1.0000x reference)
//
#include <hip/hip_runtime.h>
#include <hip/hip_bf16.h>
#include <stdint.h>

#define T_TOK 16384
#define HD    1024
#define HD2   2048
#define NE    8
#define ROWS  (2*T_TOK)   // 32768 expert-row assignments (exactly 2 per token)
#define MAXT  264         // max M-tiles at 128 rows: 32768/128 + 8
#define RTOK  32          // tokens per router block

// meta layout (ints): cnt[e] at meta[e*32] (padded to cache lines, e<8)
//   nt at meta[256]; offs[8] at meta+272; tile_e/tile_r0/tile_re at meta+288 (+MAXT,+2*MAXT)
#define M_NT    256
#define M_OFFS  272
#define M_TILES 288

typedef __bf16 bf16x8 __attribute__((ext_vector_type(8)));
typedef float f32x4 __attribute__((ext_vector_type(4)));

// async 16B global->LDS (dest = wave-uniform base + lane*16)
#define GLD16(g, l) __builtin_amdgcn_global_load_lds( \
    (const __attribute__((address_space(1))) void*)(g), \
    (__attribute__((address_space(3))) void*)(l), 16, 0, 0)

__device__ inline unsigned short f2bf(float f) {  // RNE fp32->bf16
    unsigned int u = __float_as_uint(f);
    unsigned int r = (u + 0x7fffu + ((u >> 16) & 1u)) >> 16;
    return (unsigned short)r;
}

// ------------- fp32 [E][K][N] -> bf16 [E][N][K] transpose-convert -------------
__global__ __launch_bounds__(256) void cvt_wT(const float* __restrict__ w,
                                              unsigned short* __restrict__ wt,
                                              int K, int N) {
    __shared__ float t[32][33];
    int e = blockIdx.z;
    int n0 = blockIdx.x * 32, k0 = blockIdx.y * 32;
    int r = threadIdx.x >> 3;          // 0..31
    int c4 = (threadIdx.x & 7) * 4;    // 0..28
    const float* src = w + ((size_t)e * K + k0 + r) * N + n0 + c4;
    float4 v = *(const float4*)src;
    t[r][c4] = v.x; t[r][c4+1] = v.y; t[r][c4+2] = v.z; t[r][c4+3] = v.w;
    __syncthreads();
    int cc = threadIdx.x & 7;
    ushort4 o;
    o.x = f2bf(t[cc*4+0][r]); o.y = f2bf(t[cc*4+1][r]);
    o.z = f2bf(t[cc*4+2][r]); o.w = f2bf(t[cc*4+3][r]);
    *(ushort4*)(wt + ((size_t)e * N + n0 + r) * K + k0 + cc*4) = o;
}

// ------- router: fp32 logits, top-2, block-aggregated counting, fused x->bf16 -------
__global__ __launch_bounds__(256) void router_k(const float* __restrict__ x,
        const float* __restrict__ gw, int* __restrict__ meta,
        int* __restrict__ tok_e, int* __restrict__ tok_slot, float* __restrict__ tok_w,
        unsigned short* __restrict__ xb) {
    __shared__ float g[NE * HD];                 // transposed [e][k], 32 KB
    __shared__ int   le[RTOK * 2];
    __shared__ float lw[RTOK * 2];
    __shared__ int   lslot[RTOK * 2];
    __shared__ int   lcnt[NE];
    __shared__ int   lbase[NE];
    for (int i = threadIdx.x; i < NE * HD; i += 256) {
        int k = i >> 3, e = i & 7;
        g[e * HD + k] = gw[i];
    }
    if (threadIdx.x < NE) lcnt[threadIdx.x] = 0;
    __syncthreads();

    int wave = threadIdx.x >> 6, lane = threadIdx.x & 63;
    int t0 = blockIdx.x * RTOK;
    for (int i = 0; i < RTOK / 4; i++) {         // each wave: 8 tokens
        int tt = wave * (RTOK / 4) + i;
        int t = t0 + tt;
        const float4* xr = (const float4*)(x + (size_t)t * HD);
        float acc[NE];
#pragma unroll
        for (int e = 0; e < NE; e++) acc[e] = 0.f;
#pragma unroll
        for (int j = 0; j < HD / 256; j++) {     // 4 iters of float4
            float4 xv = xr[lane + 64 * j];
            ushort4 o4;
            o4.x = f2bf(xv.x); o4.y = f2bf(xv.y);
            o4.z = f2bf(xv.z); o4.w = f2bf(xv.w);
            *(ushort4*)(xb + (size_t)t * HD + (lane + 64 * j) * 4) = o4;
#pragma unroll
            for (int e = 0; e < NE; e++) {
                float4 gv = *(const float4*)&g[e * HD + (lane + 64 * j) * 4];
                acc[e] += xv.x * gv.x + xv.y * gv.y + xv.z * gv.z + xv.w * gv.w;
            }
        }
#pragma unroll
        for (int e = 0; e < NE; e++) {
            float v = acc[e];
#pragma unroll
            for (int off = 32; off > 0; off >>= 1) v += __shfl_down(v, off, 64);
            acc[e] = v;
        }
        if (lane == 0) {
            int e1 = 0; float l1 = acc[0];
#pragma unroll
            for (int e = 1; e < NE; e++) if (acc[e] > l1) { l1 = acc[e]; e1 = e; }
            int e2 = -1; float l2 = -3.0e38f;
#pragma unroll
            for (int e = 0; e < NE; e++) if (e != e1 && acc[e] > l2) { l2 = acc[e]; e2 = e; }
            float w1 = 1.f / (1.f + expf(l2 - l1));   // softmax denom cancels in top-2 renorm
            le[tt * 2] = e1;     le[tt * 2 + 1] = e2;
            lw[tt * 2] = w1;     lw[tt * 2 + 1] = 1.f - w1;
        }
    }
    __syncthreads();
    // block-local slot assignment (LDS atomics, 8 addresses)
    if (threadIdx.x < RTOK * 2)
        lslot[threadIdx.x] = atomicAdd(&lcnt[le[threadIdx.x]], 1);
    __syncthreads();
    // one global atomic per expert per block, counters padded to cache lines
    if (threadIdx.x < NE)
        lbase[threadIdx.x] = atomicAdd(&meta[threadIdx.x * 32], lcnt[threadIdx.x]);
    __syncthreads();
    if (threadIdx.x < RTOK * 2) {
        int gi = t0 * 2 + threadIdx.x;           // global row index = token*2 + k
        int e = le[threadIdx.x];
        tok_e[gi]    = e;
        tok_slot[gi] = lbase[e] + lslot[threadIdx.x];
        tok_w[gi]    = lw[threadIdx.x];
    }
}

// ------------- offsets + M-tile table (128-row granularity, one wave) -------------
__global__ __launch_bounds__(64) void offsets_k(int* __restrict__ meta) {
    int lane = threadIdx.x;
    int cl = (lane < NE) ? meta[lane * 32] : 0;
    int cnt[NE], offs[NE], tbase[NE];
    int o = 0, tb = 0;
#pragma unroll
    for (int e = 0; e < NE; e++) {
        cnt[e] = __shfl(cl, e, 64);
        offs[e] = o;  o += cnt[e];
        tbase[e] = tb; tb += (cnt[e] + 127) >> 7;
    }
    int nt = tb;
    if (lane == 0) meta[M_NT] = nt;
    if (lane < NE) meta[M_OFFS + lane] = offs[lane];
    for (int i = lane; i < nt; i += 64) {
        int e = 0;
#pragma unroll
        for (int k = 1; k < NE; k++) if (i >= tbase[k]) e = k;
        int m = i - tbase[e];
        int r0 = offs[e] + m * 128;
        int re = offs[e] + cnt[e];
        if (r0 + 128 < re) re = r0 + 128;
        meta[M_TILES + i] = e;
        meta[M_TILES + MAXT + i] = r0;
        meta[M_TILES + 2 * MAXT + i] = re;
    }
}

// ------------- scatter token ids/weights into compact row space -------------
__global__ __launch_bounds__(256) void scatter_k(const int* __restrict__ meta,
        const int* __restrict__ tok_e, const int* __restrict__ tok_slot,
        const float* __restrict__ tok_w, int* __restrict__ rows_tok,
        float* __restrict__ rows_w) {
    int i = blockIdx.x * 256 + threadIdx.x;     // 0..ROWS-1
    const int* offs = meta + M_OFFS;
    int e = tok_e[i];
    int r = offs[e] + tok_slot[i];
    rows_tok[r] = i >> 1;
    rows_w[r] = tok_w[i];
}

// ====== 128x128 tile, BK=32, depth-3 LDS ring, 4 waves, 48 KiB LDS (3 blk/CU) ======
// r6 (depth-2, 32 KiB) achieved ~12 waves/CU but only 1-tile-interval latency
// cover (~500cy < ~900cy loaded-HBM). Depth-3: issue tile t+2 at top of t ->
// cover = 2 intervals (~1000cy >= 900), steady 12 loads in flight, vmcnt(8)
// retires exactly tile t (counted, never drains; T4). LDS 48 KiB -> 3 blk/CU
// (= r6's achieved residency, so nothing lost). 2 barriers/tile.
// Slot ledger: iter t issues into slot (t+2)%3 — freed by end-barrier of t-1;
// tail clamps (kk_=NT-1) land in slots whose reads finished; vmcnt(0) at exit.
// Bank swizzle: phys granule = g ^ ((row>>1)&3) (involution, 2-way max = free);
// pre-swizzled global source, linear LDS dest (G21). UNITS: LDS in elements;
// granule 16B = 8 elem; slot = 4096 elem; chunk c base = (c*256 + w*64)*8.

#define ISSUE(KK, NT_) do { \
    int kk_ = (KK) < (NT_) ? (KK) : (NT_) - 1; \
    int bb_ = ((KK) % 3) * 4096; \
    GLD16(pa0 + kk_ * 32, &As[bb_ + (w * 64) * 8]); \
    GLD16(pa1 + kk_ * 32, &As[bb_ + (256 + w * 64) * 8]); \
    GLD16(pb0 + kk_ * 32, &Bs[bb_ + (w * 64) * 8]); \
    GLD16(pb1 + kk_ * 32, &Bs[bb_ + (256 + w * 64) * 8]); } while (0)
#define SB0()   __builtin_amdgcn_sched_barrier(0)
#define VMW8()  do { asm volatile("s_waitcnt vmcnt(8)" ::: "memory"); SB0(); } while (0)
#define VMW0()  do { asm volatile("s_waitcnt vmcnt(0)" ::: "memory"); SB0(); } while (0)
#define BAR()   do { __builtin_amdgcn_s_barrier(); SB0(); } while (0)
#define PRIO(P) __builtin_amdgcn_s_setprio(P)

// per-K-tile compute: 8 ds_read_b128, 16 MFMA (acc[im][in]); wave tile 64x64
#define KSTEP(RB) do { \
    bf16x8 af[4], bfr[4]; \
    _Pragma("unroll") \
    for (int in_ = 0; in_ < 4; in_++) { \
        int row_ = wn * 64 + in_ * 16 + rl; \
        int ph_ = q ^ ((row_ >> 1) & 3); \
        bfr[in_] = *(const bf16x8*)&Bs[(RB) + row_ * 32 + ph_ * 8]; \
    } \
    _Pragma("unroll") \
    for (int im_ = 0; im_ < 4; im_++) { \
        int row_ = wm * 64 + im_ * 16 + rl; \
        int ph_ = q ^ ((row_ >> 1) & 3); \
        af[im_] = *(const bf16x8*)&As[(RB) + row_ * 32 + ph_ * 8]; \
    } \
    _Pragma("unroll") \
    for (int im_ = 0; im_ < 4; im_++) \
    _Pragma("unroll") \
    for (int in_ = 0; in_ < 4; in_++) \
        acc[im_][in_] = __builtin_amdgcn_mfma_f32_16x16x32_bf16( \
            af[im_], bfr[in_], acc[im_][in_], 0, 0, 0); } while (0)

// ---------------- GEMM1: hdn = relu(gather(X) @ W1 + b1), bf16 out ----------------
__global__ __launch_bounds__(256, 4) void gemm1_k(
    const unsigned short* __restrict__ Xbf,   // [T][HD]
    const unsigned short* __restrict__ W1T,   // [E][HD2][HD] (n-major, k-contig)
    const float* __restrict__ b1,             // [E][HD2]
    const int* __restrict__ meta,
    const int* __restrict__ rows_tok,
    unsigned short* __restrict__ hdn)         // [ROWS][HD2]
{
    __shared__ unsigned short As[3 * 4096];   // 24 KiB ring
    __shared__ unsigned short Bs[3 * 4096];   // 24 KiB ring
    int nt = meta[M_NT];
    int mt = blockIdx.y;
    if (mt >= nt) return;
    int e    = meta[M_TILES + mt];
    int r0   = meta[M_TILES + MAXT + mt];
    int rend = meta[M_TILES + 2 * MAXT + mt];
    int n0 = blockIdx.x * 128;

    int tid = threadIdx.x, w = tid >> 6, lane = tid & 63;
    int wm = w & 1, wn = w >> 1;
    int rl = lane & 15, q = lane >> 4;

    // staging source pointers (2 granule-chunks per operand), pre-swizzled column
    const unsigned short *pa0, *pa1, *pb0, *pb1;
    {
        int gg = tid, row = gg >> 2, lc = (gg & 3) ^ ((row >> 1) & 3);
        int grow = r0 + row; grow = grow < ROWS - 1 ? grow : ROWS - 1;
        pa0 = Xbf + (size_t)rows_tok[grow] * HD + lc * 8;
        pb0 = W1T + ((size_t)e * HD2 + n0 + row) * HD + lc * 8;
        gg = 256 + tid; row = gg >> 2; lc = (gg & 3) ^ ((row >> 1) & 3);
        grow = r0 + row; grow = grow < ROWS - 1 ? grow : ROWS - 1;
        pa1 = Xbf + (size_t)rows_tok[grow] * HD + lc * 8;
        pb1 = W1T + ((size_t)e * HD2 + n0 + row) * HD + lc * 8;
    }

    f32x4 acc[4][4];
#pragma unroll
    for (int a = 0; a < 4; a++)
#pragma unroll
    for (int b = 0; b < 4; b++)
        acc[a][b] = (f32x4){0.f, 0.f, 0.f, 0.f};

    ISSUE(0, HD / 32); ISSUE(1, HD / 32);   // prologue: tiles 0,1 in flight

#pragma unroll 3
    for (int kt = 0; kt < HD / 32; kt++) {
        ISSUE(kt + 2, HD / 32);    // 2-ahead into slot freed at end of kt-1
        SB0();
        VMW8();                    // retires tile kt's 4 loads (12 -> 8)
        BAR();                     // all waves' kt granules in LDS
        PRIO(1);
        KSTEP((kt % 3) * 4096);
        PRIO(0);
        BAR();                     // slot reads done before rewrite at kt+1
    }
    VMW0();                        // drain tail loads (LDS freed at wave exit)

    // epilogue: bias + relu + bf16 store (rows >= rend masked)
    const float* b1e = b1 + (size_t)e * HD2;
#pragma unroll
    for (int in = 0; in < 4; in++) {
        int col = n0 + wn * 64 + in * 16 + rl;
        float bias = b1e[col];
#pragma unroll
        for (int im = 0; im < 4; im++) {
            int rb2 = r0 + wm * 64 + im * 16 + q * 4;
#pragma unroll
            for (int j = 0; j < 4; j++) {
                int r = rb2 + j;
                if (r < rend) {
                    float v = acc[im][in][j] + bias;
                    v = v > 0.f ? v : 0.f;
                    hdn[(size_t)r * HD2 + col] = f2bf(v);
                }
            }
        }
    }
}

// ---------------- GEMM2: out[tok] += w * (hdn @ W2 + b2), fp32 atomics ----------------
__global__ __launch_bounds__(256, 4) void gemm2_k(
    const unsigned short* __restrict__ hdn,   // [ROWS][HD2]
    const unsigned short* __restrict__ W2T,   // [E][HD][HD2]
    const float* __restrict__ b2,             // [E][HD]
    const int* __restrict__ meta,
    const int* __restrict__ rows_tok,
    const float* __restrict__ rows_w,
    float* __restrict__ out)                  // [T][HD]
{
    __shared__ unsigned short As[3 * 4096];
    __shared__ unsigned short Bs[3 * 4096];
    int nt = meta[M_NT];
    int mt = blockIdx.y;
    if (mt >= nt) return;
    int e    = meta[M_TILES + mt];
    int r0   = meta[M_TILES + MAXT + mt];
    int rend = meta[M_TILES + 2 * MAXT + mt];
    int n0 = blockIdx.x * 128;

    int tid = threadIdx.x, w = tid >> 6, lane = tid & 63;
    int wm = w & 1, wn = w >> 1;
    int rl = lane & 15, q = lane >> 4;

    const unsigned short *pa0, *pa1, *pb0, *pb1;
    {
        int gg = tid, row = gg >> 2, lc = (gg & 3) ^ ((row >> 1) & 3);
        int grow = r0 + row; grow = grow < ROWS - 1 ? grow : ROWS - 1;
        pa0 = hdn + (size_t)grow * HD2 + lc * 8;      // hdn rows slot-contiguous
        pb0 = W2T + ((size_t)e * HD + n0 + row) * HD2 + lc * 8;
        gg = 256 + tid; row = gg >> 2; lc = (gg & 3) ^ ((row >> 1) & 3);
        grow = r0 + row; grow = grow < ROWS - 1 ? grow : ROWS - 1;
        pa1 = hdn + (size_t)grow * HD2 + lc * 8;
        pb1 = W2T + ((size_t)e * HD + n0 + row) * HD2 + lc * 8;
    }

    f32x4 acc[4][4];
#pragma unroll
    for (int a = 0; a < 4; a++)
#pragma unroll
    for (int b = 0; b < 4; b++)
        acc[a][b] = (f32x4){0.f, 0.f, 0.f, 0.f};

    ISSUE(0, HD2 / 32); ISSUE(1, HD2 / 32);

#pragma unroll 3
    for (int kt = 0; kt < HD2 / 32; kt++) {
        ISSUE(kt + 2, HD2 / 32);
        SB0();
        VMW8();
        BAR();
        PRIO(1);
        KSTEP((kt % 3) * 4096);
        PRIO(0);
        BAR();
    }
    VMW0();

    // epilogue: (acc + bias) * row_weight, atomic scatter into out (rows >= rend masked)
    const float* b2e = b2 + (size_t)e * HD;
    float bias[4];
#pragma unroll
    for (int in = 0; in < 4; in++)
        bias[in] = b2e[n0 + wn * 64 + in * 16 + rl];
#pragma unroll
    for (int im = 0; im < 4; im++) {
        int rb2 = r0 + wm * 64 + im * 16 + q * 4;
#pragma unroll
        for (int j = 0; j < 4; j++) {
            int r = rb2 + j;
            if (r < rend) {
                int tok = rows_tok[r];
                float wt = rows_w[r];
                float* op = out + (size_t)tok * HD + n0 + wn * 64;
#pragma unroll
                for (int in = 0; in < 4; in++) {
                    float v = (acc[im][in][j] + bias[in]) * wt;
                    atomicAdd(op + in * 16 + rl, v);
                }
            }
        }
    }
}

extern "C" void kernel_launch(void* const* d_in, const int* in_sizes, int n_in,
                              void* d_out, int out_size, void* d_ws, size_t ws_size,
                              hipStream_t stream) {
    const float* x  = (const float*)d_in[0];
    const float* gw = (const float*)d_in[1];
    const float* w1 = (const float*)d_in[2];
    const float* b1 = (const float*)d_in[3];
    const float* w2 = (const float*)d_in[4];
    const float* b2 = (const float*)d_in[5];
    float* out = (float*)d_out;

    uint8_t* ws = (uint8_t*)d_ws;
    unsigned short* Xbf = (unsigned short*)(ws);                  // 32 MiB
    unsigned short* W1T = (unsigned short*)(ws + 33554432ull);    // 32 MiB
    unsigned short* W2T = (unsigned short*)(ws + 67108864ull);    // 32 MiB
    unsigned short* HDN = (unsigned short*)(ws + 100663296ull);   // 128 MiB
    int*   meta     = (int*)(ws + 234881024ull);
    int*   tok_e    = meta + 2048;
    int*   tok_slot = tok_e + ROWS;
    float* tok_w    = (float*)(tok_slot + ROWS);
    int*   rows_tok = (int*)(tok_w + ROWS);
    float* rows_w   = (float*)(rows_tok + ROWS);

    hipMemsetAsync(meta, 0, 1024, stream);   // zero padded counters
    hipMemsetAsync(d_out, 0, (size_t)out_size * sizeof(float), stream);

    cvt_wT<<<dim3(HD2 / 32, HD / 32, NE), 256, 0, stream>>>(w1, W1T, HD, HD2);
    cvt_wT<<<dim3(HD / 32, HD2 / 32, NE), 256, 0, stream>>>(w2, W2T, HD2, HD);
    router_k<<<T_TOK / RTOK, 256, 0, stream>>>(x, gw, meta, tok_e, tok_slot, tok_w, Xbf);
    offsets_k<<<1, 64, 0, stream>>>(meta);
    scatter_k<<<ROWS / 256, 256, 0, stream>>>(meta, tok_e, tok_slot, tok_w, rows_tok, rows_w);
    gemm1_k<<<dim3(HD2 / 128, MAXT), 256, 0, stream>>>(Xbf, W1T, b1, meta, rows_tok, HDN);
    gemm2_k<<<dim3(HD / 128, MAXT), 256, 0, stream>>>(HDN, W2T, b2, meta, rows_tok, rows_w, out);
}

// Round 9
// 680.451 us; speedup vs baseline: 1.1020x; 1.1020x over previous
//
#include <hip/hip_runtime.h>
#include <hip/hip_bf16.h>
#include <stdint.h>

#define T_TOK 16384
#define HD    1024
#define HD2   2048
#define NE    8
#define ROWS  (2*T_TOK)   // 32768 expert-row assignments (exactly 2 per token)
#define MAXT  264         // max M-tiles at 128 rows: 32768/128 + 8
#define RTOK  32          // tokens per router block

// meta: ONLY per-expert counters now, cnt[e] at meta[e*32] (cache-line padded).
// offsets/tile table are derived in-kernel from cnt[] (offsets_k deleted).

typedef __bf16 bf16x8 __attribute__((ext_vector_type(8)));
typedef float f32x4 __attribute__((ext_vector_type(4)));
typedef unsigned short u16x8 __attribute__((ext_vector_type(8)));

// async 16B global->LDS (dest = wave-uniform base + lane*16)
#define GLD16(g, l) __builtin_amdgcn_global_load_lds( \
    (const __attribute__((address_space(1))) void*)(g), \
    (__attribute__((address_space(3))) void*)(l), 16, 0, 0)

__device__ inline unsigned short f2bf(float f) {  // RNE fp32->bf16
    unsigned int u = __float_as_uint(f);
    unsigned int r = (u + 0x7fffu + ((u >> 16) & 1u)) >> 16;
    return (unsigned short)r;
}

// ---- derive (e, r0, rend) for M-tile mt from the 8 counters; -1 e if mt>=nt ----
__device__ inline void tile_locate(const int* __restrict__ meta, int mt,
                                   int* e_out, int* r0_out, int* re_out) {
    int o = 0, tb = 0, se = -1, sr0 = 0, sre = 0;
#pragma unroll
    for (int k = 0; k < NE; k++) {
        int c = meta[k * 32];
        int t = (c + 127) >> 7;
        if (mt >= tb && mt < tb + t) {
            se = k;
            sr0 = o + (mt - tb) * 128;
            int re = o + c;
            sre = (sr0 + 128 < re) ? sr0 + 128 : re;
        }
        o += c; tb += t;
    }
    *e_out = se; *r0_out = sr0; *re_out = sre;
}

// ------- fp32 [E][K][N] -> bf16 [E][N][K] transpose-convert, w1+w2 fused -------
__global__ __launch_bounds__(256) void cvt_all(const float* __restrict__ w1,
                                               const float* __restrict__ w2,
                                               unsigned short* __restrict__ W1T,
                                               unsigned short* __restrict__ W2T) {
    __shared__ float t[32][33];
    int z = blockIdx.z;
    const float* w; unsigned short* wt; int K, N, e;
    if (z < 8) { w = w1; wt = W1T; K = HD;  N = HD2; e = z; }
    else       { w = w2; wt = W2T; K = HD2; N = HD;  e = z - 8; }
    int n0 = blockIdx.x * 32, k0 = blockIdx.y * 32;
    if (n0 >= N || k0 >= K) return;
    int r = threadIdx.x >> 3;          // 0..31
    int c4 = (threadIdx.x & 7) * 4;    // 0..28
    const float* src = w + ((size_t)e * K + k0 + r) * N + n0 + c4;
    float4 v = *(const float4*)src;
    t[r][c4] = v.x; t[r][c4+1] = v.y; t[r][c4+2] = v.z; t[r][c4+3] = v.w;
    __syncthreads();
    int cc = threadIdx.x & 7;
    ushort4 o;
    o.x = f2bf(t[cc*4+0][r]); o.y = f2bf(t[cc*4+1][r]);
    o.z = f2bf(t[cc*4+2][r]); o.w = f2bf(t[cc*4+3][r]);
    *(ushort4*)(wt + ((size_t)e * N + n0 + r) * K + k0 + cc*4) = o;
}

// ------- router: fp32 logits, top-2, block-aggregated counting, fused x->bf16 -------
__global__ __launch_bounds__(256) void router_k(const float* __restrict__ x,
        const float* __restrict__ gw, int* __restrict__ meta,
        int* __restrict__ tok_e, int* __restrict__ tok_slot, float* __restrict__ tok_w,
        unsigned short* __restrict__ xb) {
    __shared__ float g[NE * HD];                 // transposed [e][k], 32 KB
    __shared__ int   le[RTOK * 2];
    __shared__ float lw[RTOK * 2];
    __shared__ int   lslot[RTOK * 2];
    __shared__ int   lcnt[NE];
    __shared__ int   lbase[NE];
    for (int i = threadIdx.x; i < NE * HD; i += 256) {
        int k = i >> 3, e = i & 7;
        g[e * HD + k] = gw[i];
    }
    if (threadIdx.x < NE) lcnt[threadIdx.x] = 0;
    __syncthreads();

    int wave = threadIdx.x >> 6, lane = threadIdx.x & 63;
    int t0 = blockIdx.x * RTOK;
    for (int i = 0; i < RTOK / 4; i++) {         // each wave: 8 tokens
        int tt = wave * (RTOK / 4) + i;
        int t = t0 + tt;
        const float4* xr = (const float4*)(x + (size_t)t * HD);
        float acc[NE];
#pragma unroll
        for (int e = 0; e < NE; e++) acc[e] = 0.f;
#pragma unroll
        for (int j = 0; j < HD / 256; j++) {     // 4 iters of float4
            float4 xv = xr[lane + 64 * j];
            ushort4 o4;
            o4.x = f2bf(xv.x); o4.y = f2bf(xv.y);
            o4.z = f2bf(xv.z); o4.w = f2bf(xv.w);
            *(ushort4*)(xb + (size_t)t * HD + (lane + 64 * j) * 4) = o4;
#pragma unroll
            for (int e = 0; e < NE; e++) {
                float4 gv = *(const float4*)&g[e * HD + (lane + 64 * j) * 4];
                acc[e] += xv.x * gv.x + xv.y * gv.y + xv.z * gv.z + xv.w * gv.w;
            }
        }
#pragma unroll
        for (int e = 0; e < NE; e++) {
            float v = acc[e];
#pragma unroll
            for (int off = 32; off > 0; off >>= 1) v += __shfl_down(v, off, 64);
            acc[e] = v;
        }
        if (lane == 0) {
            int e1 = 0; float l1 = acc[0];
#pragma unroll
            for (int e = 1; e < NE; e++) if (acc[e] > l1) { l1 = acc[e]; e1 = e; }
            int e2 = -1; float l2 = -3.0e38f;
#pragma unroll
            for (int e = 0; e < NE; e++) if (e != e1 && acc[e] > l2) { l2 = acc[e]; e2 = e; }
            float w1 = 1.f / (1.f + expf(l2 - l1));   // softmax denom cancels in top-2 renorm
            le[tt * 2] = e1;     le[tt * 2 + 1] = e2;
            lw[tt * 2] = w1;     lw[tt * 2 + 1] = 1.f - w1;
        }
    }
    __syncthreads();
    // block-local slot assignment (LDS atomics, 8 addresses)
    if (threadIdx.x < RTOK * 2)
        lslot[threadIdx.x] = atomicAdd(&lcnt[le[threadIdx.x]], 1);
    __syncthreads();
    // one global atomic per expert per block, counters padded to cache lines
    if (threadIdx.x < NE)
        lbase[threadIdx.x] = atomicAdd(&meta[threadIdx.x * 32], lcnt[threadIdx.x]);
    __syncthreads();
    if (threadIdx.x < RTOK * 2) {
        int gi = t0 * 2 + threadIdx.x;           // global row index = token*2 + k
        int e = le[threadIdx.x];
        tok_e[gi]    = e;
        tok_slot[gi] = lbase[e] + lslot[threadIdx.x];
        tok_w[gi]    = lw[threadIdx.x];
    }
}

// ------------- scatter token ids/weights into compact row space -------------
// (computes per-expert offsets from counters directly; offsets_k deleted)
__global__ __launch_bounds__(256) void scatter_k(const int* __restrict__ meta,
        const int* __restrict__ tok_e, const int* __restrict__ tok_slot,
        const float* __restrict__ tok_w, int* __restrict__ rows_tok,
        float* __restrict__ rows_w) {
    int i = blockIdx.x * 256 + threadIdx.x;     // 0..ROWS-1
    int e = tok_e[i];
    int off = 0;
#pragma unroll
    for (int k = 0; k < NE; k++) {
        int c = meta[k * 32];
        off += (k < e) ? c : 0;
    }
    int r = off + tok_slot[i];
    rows_tok[r] = i >> 1;
    rows_w[r] = tok_w[i];
}

// ====== 128x128 tile, BK=32, depth-2 LDS ring, 4 waves, 32 KiB LDS (r6-best) ======
// Per tile: issue next tile's 4 GLD16, vmcnt(4) retires exactly the current tile
// (counted, never drains; T4), 2 barriers/tile. Bank swizzle: phys granule =
// g ^ ((row>>1)&3) (involution, 2-way max = free, m136; 0 conflicts measured).
// Pre-swizzled global source, linear LDS dest (G21). UNITS: LDS in elements;
// granule 16B = 8 elem; chunk = 256 granules; chunk c base = (c*256 + w*64)*8.

#define ISSUE(KK, NT_) do { \
    int kk_ = (KK) < (NT_) ? (KK) : (NT_) - 1; \
    int bb_ = ((KK) & 1) * 4096; \
    GLD16(pa0 + kk_ * 32, &As[bb_ + (w * 64) * 8]); \
    GLD16(pa1 + kk_ * 32, &As[bb_ + (256 + w * 64) * 8]); \
    GLD16(pb0 + kk_ * 32, &Bs[bb_ + (w * 64) * 8]); \
    GLD16(pb1 + kk_ * 32, &Bs[bb_ + (256 + w * 64) * 8]); } while (0)
#define SB0()   __builtin_amdgcn_sched_barrier(0)
#define VMW4()  do { asm volatile("s_waitcnt vmcnt(4)" ::: "memory"); SB0(); } while (0)
#define VMW0()  do { asm volatile("s_waitcnt vmcnt(0)" ::: "memory"); SB0(); } while (0)
#define BAR()   do { __builtin_amdgcn_s_barrier(); SB0(); } while (0)
#define PRIO(P) __builtin_amdgcn_s_setprio(P)

// per-K-tile compute: 8 ds_read_b128, 16 MFMA (acc[im][in]); wave tile 64x64
#define KSTEP(RB) do { \
    bf16x8 af[4], bfr[4]; \
    _Pragma("unroll") \
    for (int in_ = 0; in_ < 4; in_++) { \
        int row_ = wn * 64 + in_ * 16 + rl; \
        int ph_ = q ^ ((row_ >> 1) & 3); \
        bfr[in_] = *(const bf16x8*)&Bs[(RB) + row_ * 32 + ph_ * 8]; \
    } \
    _Pragma("unroll") \
    for (int im_ = 0; im_ < 4; im_++) { \
        int row_ = wm * 64 + im_ * 16 + rl; \
        int ph_ = q ^ ((row_ >> 1) & 3); \
        af[im_] = *(const bf16x8*)&As[(RB) + row_ * 32 + ph_ * 8]; \
    } \
    _Pragma("unroll") \
    for (int im_ = 0; im_ < 4; im_++) \
    _Pragma("unroll") \
    for (int in_ = 0; in_ < 4; in_++) \
        acc[im_][in_] = __builtin_amdgcn_mfma_f32_16x16x32_bf16( \
            af[im_], bfr[in_], acc[im_][in_], 0, 0, 0); } while (0)

// ---------------- GEMM1: hdn = relu(gather(X) @ W1 + b1), bf16 out ----------------
__global__ __launch_bounds__(256, 4) void gemm1_k(
    const unsigned short* __restrict__ Xbf,   // [T][HD]
    const unsigned short* __restrict__ W1T,   // [E][HD2][HD] (n-major, k-contig)
    const float* __restrict__ b1,             // [E][HD2]
    const int* __restrict__ meta,
    const int* __restrict__ rows_tok,
    unsigned short* __restrict__ hdn)         // [ROWS][HD2]
{
    __shared__ unsigned short As[2 * 4096];   // 16 KiB ring / epilogue cols 0..63
    __shared__ unsigned short Bs[2 * 4096];   // 16 KiB ring / epilogue cols 64..127
    int e, r0, rend;
    tile_locate(meta, blockIdx.y, &e, &r0, &rend);
    if (e < 0) return;
    int n0 = blockIdx.x * 128;

    int tid = threadIdx.x, w = tid >> 6, lane = tid & 63;
    int wm = w & 1, wn = w >> 1;
    int rl = lane & 15, q = lane >> 4;

    // staging source pointers (2 granule-chunks per operand), pre-swizzled column
    const unsigned short *pa0, *pa1, *pb0, *pb1;
    {
        int gg = tid, row = gg >> 2, lc = (gg & 3) ^ ((row >> 1) & 3);
        int grow = r0 + row; grow = grow < ROWS - 1 ? grow : ROWS - 1;
        pa0 = Xbf + (size_t)rows_tok[grow] * HD + lc * 8;
        pb0 = W1T + ((size_t)e * HD2 + n0 + row) * HD + lc * 8;
        gg = 256 + tid; row = gg >> 2; lc = (gg & 3) ^ ((row >> 1) & 3);
        grow = r0 + row; grow = grow < ROWS - 1 ? grow : ROWS - 1;
        pa1 = Xbf + (size_t)rows_tok[grow] * HD + lc * 8;
        pb1 = W1T + ((size_t)e * HD2 + n0 + row) * HD + lc * 8;
    }

    f32x4 acc[4][4];
#pragma unroll
    for (int a = 0; a < 4; a++)
#pragma unroll
    for (int b = 0; b < 4; b++)
        acc[a][b] = (f32x4){0.f, 0.f, 0.f, 0.f};

    ISSUE(0, HD / 32);             // prologue: tile 0 in flight

#pragma unroll 2
    for (int kt = 0; kt < HD / 32; kt++) {
        ISSUE(kt + 1, HD / 32);    // next tile into other slot
        SB0();
        VMW4();                    // retires tile kt's 4 loads
        BAR();                     // all waves' kt granules in LDS
        PRIO(1);
        KSTEP((kt & 1) * 4096);
        PRIO(0);
        BAR();                     // slot reads done before rewrite next iter
    }
    VMW0();                        // drain tail loads BEFORE LDS reuse below
    BAR();                         // every wave drained -> As/Bs safe to rewrite

    // --- epilogue: bias+relu -> LDS bounce -> coalesced 256B-run stores ---
    // write phase: out tile 128x128 bf16; col<64 -> As[row][c], else Bs.
    // phys granule (8 elem) = gc ^ (row&7)  (involution; spreads banks)
    {
        const float* b1e = b1 + (size_t)e * HD2;
        unsigned short* obuf = wn ? (unsigned short*)Bs : (unsigned short*)As;
#pragma unroll
        for (int in = 0; in < 4; in++) {
            int ci = in * 16 + rl;                 // col within 64-half
            float bias = b1e[n0 + wn * 64 + ci];
#pragma unroll
            for (int im = 0; im < 4; im++) {
                int rowb = wm * 64 + im * 16 + q * 4;
#pragma unroll
                for (int j = 0; j < 4; j++) {
                    int row = rowb + j;
                    float v = acc[im][in][j] + bias;
                    v = v > 0.f ? v : 0.f;
                    int gc = ci >> 3;
                    obuf[row * 64 + (((gc ^ (row & 7)) << 3) | (ci & 7))] = f2bf(v);
                }
            }
        }
    }
    BAR();
    // read-out: 8 iters; wave = 4 rows x 16 granules -> 256B contiguous per row
#pragma unroll
    for (int it = 0; it < 8; it++) {
        int row = it * 16 + (tid >> 4);
        int gran = tid & 15;
        const unsigned short* ibuf = (gran < 8) ? (const unsigned short*)As
                                                : (const unsigned short*)Bs;
        u16x8 v = *(const u16x8*)&ibuf[row * 64 + (((gran & 7) ^ (row & 7)) << 3)];
        int r = r0 + row;
        if (r < rend)
            *(u16x8*)&hdn[(size_t)r * HD2 + n0 + gran * 8] = v;
    }
}

// ---------------- GEMM2: out[tok] += w * (hdn @ W2 + b2), fp32 atomics ----------------
__global__ __launch_bounds__(256, 4) void gemm2_k(
    const unsigned short* __restrict__ hdn,   // [ROWS][HD2]
    const unsigned short* __restrict__ W2T,   // [E][HD][HD2]
    const float* __restrict__ b2,             // [E][HD]
    const int* __restrict__ meta,
    const int* __restrict__ rows_tok,
    const float* __restrict__ rows_w,
    float* __restrict__ out)                  // [T][HD]
{
    __shared__ unsigned short As[2 * 4096];
    __shared__ unsigned short Bs[2 * 4096];
    int e, r0, rend;
    tile_locate(meta, blockIdx.y, &e, &r0, &rend);
    if (e < 0) return;
    int n0 = blockIdx.x * 128;

    int tid = threadIdx.x, w = tid >> 6, lane = tid & 63;
    int wm = w & 1, wn = w >> 1;
    int rl = lane & 15, q = lane >> 4;

    const unsigned short *pa0, *pa1, *pb0, *pb1;
    {
        int gg = tid, row = gg >> 2, lc = (gg & 3) ^ ((row >> 1) & 3);
        int grow = r0 + row; grow = grow < ROWS - 1 ? grow : ROWS - 1;
        pa0 = hdn + (size_t)grow * HD2 + lc * 8;      // hdn rows slot-contiguous
        pb0 = W2T + ((size_t)e * HD + n0 + row) * HD2 + lc * 8;
        gg = 256 + tid; row = gg >> 2; lc = (gg & 3) ^ ((row >> 1) & 3);
        grow = r0 + row; grow = grow < ROWS - 1 ? grow : ROWS - 1;
        pa1 = hdn + (size_t)grow * HD2 + lc * 8;
        pb1 = W2T + ((size_t)e * HD + n0 + row) * HD2 + lc * 8;
    }

    f32x4 acc[4][4];
#pragma unroll
    for (int a = 0; a < 4; a++)
#pragma unroll
    for (int b = 0; b < 4; b++)
        acc[a][b] = (f32x4){0.f, 0.f, 0.f, 0.f};

    ISSUE(0, HD2 / 32);

#pragma unroll 2
    for (int kt = 0; kt < HD2 / 32; kt++) {
        ISSUE(kt + 1, HD2 / 32);
        SB0();
        VMW4();
        BAR();
        PRIO(1);
        KSTEP((kt & 1) * 4096);
        PRIO(0);
        BAR();
    }
    VMW0();

    // epilogue: (acc + bias) * row_weight, atomic scatter into out (rows >= rend masked)
    const float* b2e = b2 + (size_t)e * HD;
    float bias[4];
#pragma unroll
    for (int in = 0; in < 4; in++)
        bias[in] = b2e[n0 + wn * 64 + in * 16 + rl];
#pragma unroll
    for (int im = 0; im < 4; im++) {
        int rb2 = r0 + wm * 64 + im * 16 + q * 4;
#pragma unroll
        for (int j = 0; j < 4; j++) {
            int r = rb2 + j;
            if (r < rend) {
                int tok = rows_tok[r];
                float wt = rows_w[r];
                float* op = out + (size_t)tok * HD + n0 + wn * 64;
#pragma unroll
                for (int in = 0; in < 4; in++) {
                    float v = (acc[im][in][j] + bias[in]) * wt;
                    atomicAdd(op + in * 16 + rl, v);
                }
            }
        }
    }
}

extern "C" void kernel_launch(void* const* d_in, const int* in_sizes, int n_in,
                              void* d_out, int out_size, void* d_ws, size_t ws_size,
                              hipStream_t stream) {
    const float* x  = (const float*)d_in[0];
    const float* gw = (const float*)d_in[1];
    const float* w1 = (const float*)d_in[2];
    const float* b1 = (const float*)d_in[3];
    const float* w2 = (const float*)d_in[4];
    const float* b2 = (const float*)d_in[5];
    float* out = (float*)d_out;

    uint8_t* ws = (uint8_t*)d_ws;
    unsigned short* Xbf = (unsigned short*)(ws);                  // 32 MiB
    unsigned short* W1T = (unsigned short*)(ws + 33554432ull);    // 32 MiB
    unsigned short* W2T = (unsigned short*)(ws + 67108864ull);    // 32 MiB
    unsigned short* HDN = (unsigned short*)(ws + 100663296ull);   // 128 MiB
    int*   meta     = (int*)(ws + 234881024ull);
    int*   tok_e    = meta + 2048;
    int*   tok_slot = tok_e + ROWS;
    float* tok_w    = (float*)(tok_slot + ROWS);
    int*   rows_tok = (int*)(tok_w + ROWS);
    float* rows_w   = (float*)(rows_tok + ROWS);

    hipMemsetAsync(meta, 0, 1024, stream);   // zero padded counters
    hipMemsetAsync(d_out, 0, (size_t)out_size * sizeof(float), stream);

    cvt_all<<<dim3(64, 64, 16), 256, 0, stream>>>(w1, w2, W1T, W2T);
    router_k<<<T_TOK / RTOK, 256, 0, stream>>>(x, gw, meta, tok_e, tok_slot, tok_w, Xbf);
    scatter_k<<<ROWS / 256, 256, 0, stream>>>(meta, tok_e, tok_slot, tok_w, rows_tok, rows_w);
    gemm1_k<<<dim3(HD2 / 128, MAXT), 256, 0, stream>>>(Xbf, W1T, b1, meta, rows_tok, HDN);
    gemm2_k<<<dim3(HD / 128, MAXT), 256, 0, stream>>>(HDN, W2T, b2, meta, rows_tok, rows_w, out);
}

// Round 10
// 671.492 us; speedup vs baseline: 1.1167x; 1.0133x over previous
//
#include <hip/hip_runtime.h>
#include <hip/hip_bf16.h>
#include <stdint.h>

#define T_TOK 16384
#define HD    1024
#define HD2   2048
#define NE    8
#define ROWS  (2*T_TOK)   // 32768 expert-row assignments (exactly 2 per token)
#define MAXT  264         // max M-tiles at 128 rows: 32768/128 + 8
#define RTOK  32          // tokens per router block

// meta: ONLY per-expert counters, cnt[e] at meta[e*32] (cache-line padded).
// offsets/tile table derived in-kernel from cnt[].

typedef __bf16 bf16x8 __attribute__((ext_vector_type(8)));
typedef float f32x4 __attribute__((ext_vector_type(4)));
typedef unsigned short u16x8 __attribute__((ext_vector_type(8)));

// async 16B global->LDS (dest = wave-uniform base + lane*16)
#define GLD16(g, l) __builtin_amdgcn_global_load_lds( \
    (const __attribute__((address_space(1))) void*)(g), \
    (__attribute__((address_space(3))) void*)(l), 16, 0, 0)

__device__ inline unsigned short f2bf(float f) {  // RNE fp32->bf16
    unsigned int u = __float_as_uint(f);
    unsigned int r = (u + 0x7fffu + ((u >> 16) & 1u)) >> 16;
    return (unsigned short)r;
}

// ---- derive (e, r0, rend) for M-tile mt from the 8 counters; -1 e if mt>=nt ----
__device__ inline void tile_locate(const int* __restrict__ meta, int mt,
                                   int* e_out, int* r0_out, int* re_out) {
    int o = 0, tb = 0, se = -1, sr0 = 0, sre = 0;
#pragma unroll
    for (int k = 0; k < NE; k++) {
        int c = meta[k * 32];
        int t = (c + 127) >> 7;
        if (mt >= tb && mt < tb + t) {
            se = k;
            sr0 = o + (mt - tb) * 128;
            int re = o + c;
            sre = (sr0 + 128 < re) ? sr0 + 128 : re;
        }
        o += c; tb += t;
    }
    *e_out = se; *r0_out = sr0; *re_out = sre;
}

// ------- fp32 [E][K][N] -> bf16 [E][N][K] transpose-convert, w1+w2 fused -------
__global__ __launch_bounds__(256) void cvt_all(const float* __restrict__ w1,
                                               const float* __restrict__ w2,
                                               unsigned short* __restrict__ W1T,
                                               unsigned short* __restrict__ W2T) {
    __shared__ float t[32][33];
    int z = blockIdx.z;
    const float* w; unsigned short* wt; int K, N, e;
    if (z < 8) { w = w1; wt = W1T; K = HD;  N = HD2; e = z; }
    else       { w = w2; wt = W2T; K = HD2; N = HD;  e = z - 8; }
    int n0 = blockIdx.x * 32, k0 = blockIdx.y * 32;
    if (n0 >= N || k0 >= K) return;
    int r = threadIdx.x >> 3;          // 0..31
    int c4 = (threadIdx.x & 7) * 4;    // 0..28
    const float* src = w + ((size_t)e * K + k0 + r) * N + n0 + c4;
    float4 v = *(const float4*)src;
    t[r][c4] = v.x; t[r][c4+1] = v.y; t[r][c4+2] = v.z; t[r][c4+3] = v.w;
    __syncthreads();
    int cc = threadIdx.x & 7;
    ushort4 o;
    o.x = f2bf(t[cc*4+0][r]); o.y = f2bf(t[cc*4+1][r]);
    o.z = f2bf(t[cc*4+2][r]); o.w = f2bf(t[cc*4+3][r]);
    *(ushort4*)(wt + ((size_t)e * N + n0 + r) * K + k0 + cc*4) = o;
}

// ------- router: fp32 logits, top-2, block-aggregated counting, fused x->bf16 -------
__global__ __launch_bounds__(256) void router_k(const float* __restrict__ x,
        const float* __restrict__ gw, int* __restrict__ meta,
        int* __restrict__ tok_e, int* __restrict__ tok_slot, float* __restrict__ tok_w,
        unsigned short* __restrict__ xb) {
    __shared__ float g[NE * HD];                 // transposed [e][k], 32 KB
    __shared__ int   le[RTOK * 2];
    __shared__ float lw[RTOK * 2];
    __shared__ int   lslot[RTOK * 2];
    __shared__ int   lcnt[NE];
    __shared__ int   lbase[NE];
    for (int i = threadIdx.x; i < NE * HD; i += 256) {
        int k = i >> 3, e = i & 7;
        g[e * HD + k] = gw[i];
    }
    if (threadIdx.x < NE) lcnt[threadIdx.x] = 0;
    __syncthreads();

    int wave = threadIdx.x >> 6, lane = threadIdx.x & 63;
    int t0 = blockIdx.x * RTOK;
    for (int i = 0; i < RTOK / 4; i++) {         // each wave: 8 tokens
        int tt = wave * (RTOK / 4) + i;
        int t = t0 + tt;
        const float4* xr = (const float4*)(x + (size_t)t * HD);
        float acc[NE];
#pragma unroll
        for (int e = 0; e < NE; e++) acc[e] = 0.f;
#pragma unroll
        for (int j = 0; j < HD / 256; j++) {     // 4 iters of float4
            float4 xv = xr[lane + 64 * j];
            ushort4 o4;
            o4.x = f2bf(xv.x); o4.y = f2bf(xv.y);
            o4.z = f2bf(xv.z); o4.w = f2bf(xv.w);
            *(ushort4*)(xb + (size_t)t * HD + (lane + 64 * j) * 4) = o4;
#pragma unroll
            for (int e = 0; e < NE; e++) {
                float4 gv = *(const float4*)&g[e * HD + (lane + 64 * j) * 4];
                acc[e] += xv.x * gv.x + xv.y * gv.y + xv.z * gv.z + xv.w * gv.w;
            }
        }
#pragma unroll
        for (int e = 0; e < NE; e++) {
            float v = acc[e];
#pragma unroll
            for (int off = 32; off > 0; off >>= 1) v += __shfl_down(v, off, 64);
            acc[e] = v;
        }
        if (lane == 0) {
            int e1 = 0; float l1 = acc[0];
#pragma unroll
            for (int e = 1; e < NE; e++) if (acc[e] > l1) { l1 = acc[e]; e1 = e; }
            int e2 = -1; float l2 = -3.0e38f;
#pragma unroll
            for (int e = 0; e < NE; e++) if (e != e1 && acc[e] > l2) { l2 = acc[e]; e2 = e; }
            float w1 = 1.f / (1.f + expf(l2 - l1));   // softmax denom cancels in top-2 renorm
            le[tt * 2] = e1;     le[tt * 2 + 1] = e2;
            lw[tt * 2] = w1;     lw[tt * 2 + 1] = 1.f - w1;
        }
    }
    __syncthreads();
    // block-local slot assignment (LDS atomics, 8 addresses)
    if (threadIdx.x < RTOK * 2)
        lslot[threadIdx.x] = atomicAdd(&lcnt[le[threadIdx.x]], 1);
    __syncthreads();
    // one global atomic per expert per block, counters padded to cache lines
    if (threadIdx.x < NE)
        lbase[threadIdx.x] = atomicAdd(&meta[threadIdx.x * 32], lcnt[threadIdx.x]);
    __syncthreads();
    if (threadIdx.x < RTOK * 2) {
        int gi = t0 * 2 + threadIdx.x;           // global row index = token*2 + k
        int e = le[threadIdx.x];
        tok_e[gi]    = e;
        tok_slot[gi] = lbase[e] + lslot[threadIdx.x];
        tok_w[gi]    = lw[threadIdx.x];
    }
}

// ------------- scatter token ids/weights into compact row space -------------
__global__ __launch_bounds__(256) void scatter_k(const int* __restrict__ meta,
        const int* __restrict__ tok_e, const int* __restrict__ tok_slot,
        const float* __restrict__ tok_w, int* __restrict__ rows_tok,
        float* __restrict__ rows_w) {
    int i = blockIdx.x * 256 + threadIdx.x;     // 0..ROWS-1
    int e = tok_e[i];
    int off = 0;
#pragma unroll
    for (int k = 0; k < NE; k++) {
        int c = meta[k * 32];
        off += (k < e) ? c : 0;
    }
    int r = off + tok_slot[i];
    rows_tok[r] = i >> 1;
    rows_w[r] = tok_w[i];
}

// ====== 128x128 tile, BK=32, depth-2 LDS ring, 4 waves, 32 KiB LDS ======
// XCD-affinity grid (r10): 1-D grid, id decode puts ALL N-blocks of one M-tile
// in the same residue class r=id&7 -> same XCD under round-robin dispatch ->
// the shared A-panel (512 KB) is fetched into that XCD's L2 ONCE and reused
// 8x/16x, instead of 8 XCDs each fetching it (r9: FETCH 3.5x footprint).
//   r = id&7; q = id>>3; x = q&(NX-1); mt = (q>>log2NX)*8 + r   (bijective)
// Inner loop unchanged from r9 (passed, 680us): vmcnt(4) counted, 2 bar/tile,
// swizzle phys granule = g ^ ((row>>1)&3), pre-swizzled source, linear dest.

#define ISSUE(KK, NT_) do { \
    int kk_ = (KK) < (NT_) ? (KK) : (NT_) - 1; \
    int bb_ = ((KK) & 1) * 4096; \
    GLD16(pa0 + kk_ * 32, &As[bb_ + (w * 64) * 8]); \
    GLD16(pa1 + kk_ * 32, &As[bb_ + (256 + w * 64) * 8]); \
    GLD16(pb0 + kk_ * 32, &Bs[bb_ + (w * 64) * 8]); \
    GLD16(pb1 + kk_ * 32, &Bs[bb_ + (256 + w * 64) * 8]); } while (0)
#define SB0()   __builtin_amdgcn_sched_barrier(0)
#define VMW4()  do { asm volatile("s_waitcnt vmcnt(4)" ::: "memory"); SB0(); } while (0)
#define VMW0()  do { asm volatile("s_waitcnt vmcnt(0)" ::: "memory"); SB0(); } while (0)
#define BAR()   do { __builtin_amdgcn_s_barrier(); SB0(); } while (0)
#define PRIO(P) __builtin_amdgcn_s_setprio(P)

// per-K-tile compute: 8 ds_read_b128, 16 MFMA (acc[im][in]); wave tile 64x64
#define KSTEP(RB) do { \
    bf16x8 af[4], bfr[4]; \
    _Pragma("unroll") \
    for (int in_ = 0; in_ < 4; in_++) { \
        int row_ = wn * 64 + in_ * 16 + rl; \
        int ph_ = q ^ ((row_ >> 1) & 3); \
        bfr[in_] = *(const bf16x8*)&Bs[(RB) + row_ * 32 + ph_ * 8]; \
    } \
    _Pragma("unroll") \
    for (int im_ = 0; im_ < 4; im_++) { \
        int row_ = wm * 64 + im_ * 16 + rl; \
        int ph_ = q ^ ((row_ >> 1) & 3); \
        af[im_] = *(const bf16x8*)&As[(RB) + row_ * 32 + ph_ * 8]; \
    } \
    _Pragma("unroll") \
    for (int im_ = 0; im_ < 4; im_++) \
    _Pragma("unroll") \
    for (int in_ = 0; in_ < 4; in_++) \
        acc[im_][in_] = __builtin_amdgcn_mfma_f32_16x16x32_bf16( \
            af[im_], bfr[in_], acc[im_][in_], 0, 0, 0); } while (0)

// ---------------- GEMM1: hdn = relu(gather(X) @ W1 + b1), bf16 out ----------------
__global__ __launch_bounds__(256, 4) void gemm1_k(
    const unsigned short* __restrict__ Xbf,   // [T][HD]
    const unsigned short* __restrict__ W1T,   // [E][HD2][HD] (n-major, k-contig)
    const float* __restrict__ b1,             // [E][HD2]
    const int* __restrict__ meta,
    const int* __restrict__ rows_tok,
    unsigned short* __restrict__ hdn)         // [ROWS][HD2]
{
    __shared__ unsigned short As[2 * 4096];   // 16 KiB ring / epilogue cols 0..63
    __shared__ unsigned short Bs[2 * 4096];   // 16 KiB ring / epilogue cols 64..127
    // XCD-affinity decode: NX=16 N-tiles; all 16 blocks of one mt share r=id&7
    int id = blockIdx.x;
    int r_ = id & 7, qq = id >> 3;
    int xx = qq & 15, mt = (qq >> 4) * 8 + r_;
    int e, r0, rend;
    tile_locate(meta, mt, &e, &r0, &rend);
    if (e < 0) return;
    int n0 = xx * 128;

    int tid = threadIdx.x, w = tid >> 6, lane = tid & 63;
    int wm = w & 1, wn = w >> 1;
    int rl = lane & 15, q = lane >> 4;

    // staging source pointers (2 granule-chunks per operand), pre-swizzled column
    const unsigned short *pa0, *pa1, *pb0, *pb1;
    {
        int gg = tid, row = gg >> 2, lc = (gg & 3) ^ ((row >> 1) & 3);
        int grow = r0 + row; grow = grow < ROWS - 1 ? grow : ROWS - 1;
        pa0 = Xbf + (size_t)rows_tok[grow] * HD + lc * 8;
        pb0 = W1T + ((size_t)e * HD2 + n0 + row) * HD + lc * 8;
        gg = 256 + tid; row = gg >> 2; lc = (gg & 3) ^ ((row >> 1) & 3);
        grow = r0 + row; grow = grow < ROWS - 1 ? grow : ROWS - 1;
        pa1 = Xbf + (size_t)rows_tok[grow] * HD + lc * 8;
        pb1 = W1T + ((size_t)e * HD2 + n0 + row) * HD + lc * 8;
    }

    f32x4 acc[4][4];
#pragma unroll
    for (int a = 0; a < 4; a++)
#pragma unroll
    for (int b = 0; b < 4; b++)
        acc[a][b] = (f32x4){0.f, 0.f, 0.f, 0.f};

    ISSUE(0, HD / 32);             // prologue: tile 0 in flight

#pragma unroll 2
    for (int kt = 0; kt < HD / 32; kt++) {
        ISSUE(kt + 1, HD / 32);    // next tile into other slot
        SB0();
        VMW4();                    // retires tile kt's 4 loads
        BAR();                     // all waves' kt granules in LDS
        PRIO(1);
        KSTEP((kt & 1) * 4096);
        PRIO(0);
        BAR();                     // slot reads done before rewrite next iter
    }
    VMW0();                        // drain tail loads BEFORE LDS reuse below
    BAR();                         // every wave drained -> As/Bs safe to rewrite

    // --- epilogue: bias+relu -> LDS bounce -> coalesced 256B-run stores ---
    {
        const float* b1e = b1 + (size_t)e * HD2;
        unsigned short* obuf = wn ? (unsigned short*)Bs : (unsigned short*)As;
#pragma unroll
        for (int in = 0; in < 4; in++) {
            int ci = in * 16 + rl;                 // col within 64-half
            float bias = b1e[n0 + wn * 64 + ci];
#pragma unroll
            for (int im = 0; im < 4; im++) {
                int rowb = wm * 64 + im * 16 + q * 4;
#pragma unroll
                for (int j = 0; j < 4; j++) {
                    int row = rowb + j;
                    float v = acc[im][in][j] + bias;
                    v = v > 0.f ? v : 0.f;
                    int gc = ci >> 3;
                    obuf[row * 64 + (((gc ^ (row & 7)) << 3) | (ci & 7))] = f2bf(v);
                }
            }
        }
    }
    BAR();
    // read-out: 8 iters; wave = 4 rows x 16 granules -> 256B contiguous per row
#pragma unroll
    for (int it = 0; it < 8; it++) {
        int row = it * 16 + (tid >> 4);
        int gran = tid & 15;
        const unsigned short* ibuf = (gran < 8) ? (const unsigned short*)As
                                                : (const unsigned short*)Bs;
        u16x8 v = *(const u16x8*)&ibuf[row * 64 + (((gran & 7) ^ (row & 7)) << 3)];
        int r = r0 + row;
        if (r < rend)
            *(u16x8*)&hdn[(size_t)r * HD2 + n0 + gran * 8] = v;
    }
}

// ---------------- GEMM2: out[tok] += w * (hdn @ W2 + b2), fp32 atomics ----------------
__global__ __launch_bounds__(256, 4) void gemm2_k(
    const unsigned short* __restrict__ hdn,   // [ROWS][HD2]
    const unsigned short* __restrict__ W2T,   // [E][HD][HD2]
    const float* __restrict__ b2,             // [E][HD]
    const int* __restrict__ meta,
    const int* __restrict__ rows_tok,
    const float* __restrict__ rows_w,
    float* __restrict__ out)                  // [T][HD]
{
    __shared__ unsigned short As[2 * 4096];
    __shared__ unsigned short Bs[2 * 4096];
    // XCD-affinity decode: NX=8 N-tiles; all 8 blocks of one mt share r=id&7
    int id = blockIdx.x;
    int r_ = id & 7, qq = id >> 3;
    int xx = qq & 7, mt = (qq >> 3) * 8 + r_;
    int e, r0, rend;
    tile_locate(meta, mt, &e, &r0, &rend);
    if (e < 0) return;
    int n0 = xx * 128;

    int tid = threadIdx.x, w = tid >> 6, lane = tid & 63;
    int wm = w & 1, wn = w >> 1;
    int rl = lane & 15, q = lane >> 4;

    const unsigned short *pa0, *pa1, *pb0, *pb1;
    {
        int gg = tid, row = gg >> 2, lc = (gg & 3) ^ ((row >> 1) & 3);
        int grow = r0 + row; grow = grow < ROWS - 1 ? grow : ROWS - 1;
        pa0 = hdn + (size_t)grow * HD2 + lc * 8;      // hdn rows slot-contiguous
        pb0 = W2T + ((size_t)e * HD + n0 + row) * HD2 + lc * 8;
        gg = 256 + tid; row = gg >> 2; lc = (gg & 3) ^ ((row >> 1) & 3);
        grow = r0 + row; grow = grow < ROWS - 1 ? grow : ROWS - 1;
        pa1 = hdn + (size_t)grow * HD2 + lc * 8;
        pb1 = W2T + ((size_t)e * HD + n0 + row) * HD2 + lc * 8;
    }

    f32x4 acc[4][4];
#pragma unroll
    for (int a = 0; a < 4; a++)
#pragma unroll
    for (int b = 0; b < 4; b++)
        acc[a][b] = (f32x4){0.f, 0.f, 0.f, 0.f};

    ISSUE(0, HD2 / 32);

#pragma unroll 2
    for (int kt = 0; kt < HD2 / 32; kt++) {
        ISSUE(kt + 1, HD2 / 32);
        SB0();
        VMW4();
        BAR();
        PRIO(1);
        KSTEP((kt & 1) * 4096);
        PRIO(0);
        BAR();
    }
    VMW0();

    // epilogue: (acc + bias) * row_weight, atomic scatter into out (rows >= rend masked)
    const float* b2e = b2 + (size_t)e * HD;
    float bias[4];
#pragma unroll
    for (int in = 0; in < 4; in++)
        bias[in] = b2e[n0 + wn * 64 + in * 16 + rl];
#pragma unroll
    for (int im = 0; im < 4; im++) {
        int rb2 = r0 + wm * 64 + im * 16 + q * 4;
#pragma unroll
        for (int j = 0; j < 4; j++) {
            int r = rb2 + j;
            if (r < rend) {
                int tok = rows_tok[r];
                float wt = rows_w[r];
                float* op = out + (size_t)tok * HD + n0 + wn * 64;
#pragma unroll
                for (int in = 0; in < 4; in++) {
                    float v = (acc[im][in][j] + bias[in]) * wt;
                    atomicAdd(op + in * 16 + rl, v);
                }
            }
        }
    }
}

extern "C" void kernel_launch(void* const* d_in, const int* in_sizes, int n_in,
                              void* d_out, int out_size, void* d_ws, size_t ws_size,
                              hipStream_t stream) {
    const float* x  = (const float*)d_in[0];
    const float* gw = (const float*)d_in[1];
    const float* w1 = (const float*)d_in[2];
    const float* b1 = (const float*)d_in[3];
    const float* w2 = (const float*)d_in[4];
    const float* b2 = (const float*)d_in[5];
    float* out = (float*)d_out;

    uint8_t* ws = (uint8_t*)d_ws;
    unsigned short* Xbf = (unsigned short*)(ws);                  // 32 MiB
    unsigned short* W1T = (unsigned short*)(ws + 33554432ull);    // 32 MiB
    unsigned short* W2T = (unsigned short*)(ws + 67108864ull);    // 32 MiB
    unsigned short* HDN = (unsigned short*)(ws + 100663296ull);   // 128 MiB
    int*   meta     = (int*)(ws + 234881024ull);
    int*   tok_e    = meta + 2048;
    int*   tok_slot = tok_e + ROWS;
    float* tok_w    = (float*)(tok_slot + ROWS);
    int*   rows_tok = (int*)(tok_w + ROWS);
    float* rows_w   = (float*)(rows_tok + ROWS);

    hipMemsetAsync(meta, 0, 1024, stream);   // zero padded counters
    hipMemsetAsync(d_out, 0, (size_t)out_size * sizeof(float), stream);

    cvt_all<<<dim3(64, 64, 16), 256, 0, stream>>>(w1, w2, W1T, W2T);
    router_k<<<T_TOK / RTOK, 256, 0, stream>>>(x, gw, meta, tok_e, tok_slot, tok_w, Xbf);
    scatter_k<<<ROWS / 256, 256, 0, stream>>>(meta, tok_e, tok_slot, tok_w, rows_tok, rows_w);
    gemm1_k<<<16 * MAXT, 256, 0, stream>>>(Xbf, W1T, b1, meta, rows_tok, HDN);
    gemm2_k<<<8 * MAXT, 256, 0, stream>>>(HDN, W2T, b2, meta, rows_tok, rows_w, out);
}